// Round 9
// baseline (689.019 us; speedup 1.0000x reference)
//
#include <hip/hip_runtime.h>

#define NDIM 64
#define EDIM 16
#define SCAN_BS 256
#define SCAN_TILE 2048   // SCAN_BS * 8

typedef __attribute__((ext_vector_type(8))) short short8;   // 8 x bf16 (4 VGPR)
typedef __attribute__((ext_vector_type(4))) float f32x4;    // MFMA acc
typedef __attribute__((ext_vector_type(4))) float f4;       // raw float4 (no ctor)
typedef __attribute__((ext_vector_type(4))) unsigned int u32x4;

// ---------------- scalar (constant AS) load helpers ----------------
#define AS4 __attribute__((address_space(4)))
__device__ inline const AS4 int* cs_i(const int* p) {
    return (const AS4 int*)(unsigned long long)p;
}
__device__ inline const AS4 u32x4* cs_u4(const unsigned int* p) {
    return (const AS4 u32x4*)(unsigned long long)p;
}

// exact bf16->fp32 reconstruction (scalar-pipe friendly: shift / and)
#define BF_LO(u) __uint_as_float((u) << 16)
#define BF_HI(u) __uint_as_float((u) & 0xffff0000u)

// ---------------- bf16 helpers ----------------
__device__ inline unsigned short f2bf_rne(float f) {
    unsigned int u = __float_as_uint(f);
    unsigned int r = u + 0x7FFFu + ((u >> 16) & 1u);
    return (unsigned short)(r >> 16);
}
__device__ inline float bf2f(unsigned short h) {
    return __uint_as_float(((unsigned int)h) << 16);
}
__device__ inline unsigned int pack2(float a, float b) {
    return (unsigned int)f2bf_rne(a) | ((unsigned int)f2bf_rne(b) << 16);
}
__device__ inline void cvt8(const float4 v0, const float4 v1, short8& hi, short8& lo) {
    float v[8] = {v0.x, v0.y, v0.z, v0.w, v1.x, v1.y, v1.z, v1.w};
#pragma unroll
    for (int j = 0; j < 8; ++j) {
        unsigned short h = f2bf_rne(v[j]);
        hi[j] = (short)h;
        lo[j] = (short)f2bf_rne(v[j] - bf2f(h));
    }
}

// ---------------- CSR build ----------------

__global__ __launch_bounds__(256) void hist_kernel(const int* __restrict__ edge_index,
                                                   int* __restrict__ deg, int E) {
    int e = blockIdx.x * blockDim.x + threadIdx.x;
    if (e < E) atomicAdd(&deg[edge_index[E + e]], 1);   // dst row
}

__global__ __launch_bounds__(SCAN_BS) void scan_tile_kernel(const int* __restrict__ deg,
                                                            int* __restrict__ excl,
                                                            int* __restrict__ tsum, int n) {
    __shared__ int sdata[SCAN_BS];
    int base = blockIdx.x * SCAN_TILE + threadIdx.x * 8;
    int v[8]; int s = 0;
#pragma unroll
    for (int j = 0; j < 8; ++j) { int idx = base + j; int val = (idx < n) ? deg[idx] : 0; v[j] = val; s += val; }
    sdata[threadIdx.x] = s;
    __syncthreads();
    for (int off = 1; off < SCAN_BS; off <<= 1) {
        int t = (threadIdx.x >= (unsigned)off) ? sdata[threadIdx.x - off] : 0;
        __syncthreads();
        sdata[threadIdx.x] += t;
        __syncthreads();
    }
    int incl = sdata[threadIdx.x];
    if (threadIdx.x == SCAN_BS - 1) tsum[blockIdx.x] = incl;
    int run = incl - s;
#pragma unroll
    for (int j = 0; j < 8; ++j) { int idx = base + j; if (idx < n) excl[idx] = run; run += v[j]; }
}

__global__ void scan_sums_kernel(int* tsum, int ntiles) {
    if (threadIdx.x == 0 && blockIdx.x == 0) {
        int run = 0;
        for (int i = 0; i < ntiles; ++i) { int t = tsum[i]; tsum[i] = run; run += t; }
    }
}

__global__ __launch_bounds__(256) void scan_add_kernel(int* __restrict__ rowptr,
                                                       const int* __restrict__ tsum,
                                                       int* __restrict__ fillc, int n, int E) {
    int i = blockIdx.x * blockDim.x + threadIdx.x;
    if (i < n) {
        int v = rowptr[i] + tsum[i / SCAN_TILE];
        rowptr[i] = v;
        fillc[i] = v;
    }
    if (i == 0) rowptr[n] = E;
}

// scatter ONLY eids (random 4B writes — measured line-allocate bound, ~81us;
// nt store made no difference. Two-level LDS sort is the known next lever.)
__global__ __launch_bounds__(256) void fill_kernel(const int* __restrict__ edge_index,
                                                   int* __restrict__ fillc,
                                                   int* __restrict__ eids, int E) {
    int e = blockIdx.x * blockDim.x + threadIdx.x;
    if (e < E) {
        int d = edge_index[E + e];
        int pos = atomicAdd(&fillc[d], 1);
        __builtin_nontemporal_store(e, &eids[pos]);
    }
}

// gather-style permute: coalesced eids read; random reads (L3-resident);
// writes (gea bf16-packed, srcs, gdst) fully coalesced.
__global__ __launch_bounds__(256) void permute_kernel(const int* __restrict__ eids,
                                                      const int* __restrict__ edge_index,
                                                      const float4* __restrict__ ea,
                                                      u32x4* __restrict__ gea,
                                                      int* __restrict__ srcs,
                                                      int* __restrict__ gdst, int E) {
    int p = blockIdx.x * blockDim.x + threadIdx.x;
    if (p < E) {
        int e = eids[p];
        srcs[p] = edge_index[e];
        gdst[p] = edge_index[E + e];
        float4 r0 = ea[(size_t)e*4+0], r1 = ea[(size_t)e*4+1],
               r2 = ea[(size_t)e*4+2], r3 = ea[(size_t)e*4+3];
        u32x4 d0, d1;
        d0.x = pack2(r0.x, r0.y); d0.y = pack2(r0.z, r0.w);
        d0.z = pack2(r1.x, r1.y); d0.w = pack2(r1.z, r1.w);
        d1.x = pack2(r2.x, r2.y); d1.y = pack2(r2.z, r2.w);
        d1.z = pack2(r3.x, r3.y); d1.w = pack2(r3.z, r3.w);
        gea[(size_t)p*2+0] = d0; gea[(size_t)p*2+1] = d1;
    }
}

// layer-0 init: hacc = (1+eps0)*x (fp32) and xbf = bf16(x)
__global__ __launch_bounds__(256) void init_kernel(const float4* __restrict__ x,
                                                   float4* __restrict__ h,
                                                   unsigned short* __restrict__ xbf,
                                                   const float* __restrict__ eps, int n4) {
    float e1 = 1.0f + eps[0];
    int i = blockIdx.x * blockDim.x + threadIdx.x;
    int stride = gridDim.x * blockDim.x;
    for (; i < n4; i += stride) {
        float4 v = x[i];
        uint2 u;
        u.x = pack2(v.x, v.y);
        u.y = pack2(v.z, v.w);
        *(uint2*)(xbf + (size_t)i * 4) = u;
        v.x *= e1; v.y *= e1; v.z *= e1; v.w *= e1;
        h[i] = v;
    }
}

// 16 fma with bf16-packed edge attrs (U0,U1 = 8 dwords); unpack is exact.
#define EDGE_FMA16B(m, U0, U1)                                          \
    m = fmaf(BF_LO(U0.x), le[ 0], m); m = fmaf(BF_HI(U0.x), le[ 1], m); \
    m = fmaf(BF_LO(U0.y), le[ 2], m); m = fmaf(BF_HI(U0.y), le[ 3], m); \
    m = fmaf(BF_LO(U0.z), le[ 4], m); m = fmaf(BF_HI(U0.z), le[ 5], m); \
    m = fmaf(BF_LO(U0.w), le[ 6], m); m = fmaf(BF_HI(U0.w), le[ 7], m); \
    m = fmaf(BF_LO(U1.x), le[ 8], m); m = fmaf(BF_HI(U1.x), le[ 9], m); \
    m = fmaf(BF_LO(U1.y), le[10], m); m = fmaf(BF_HI(U1.y), le[11], m); \
    m = fmaf(BF_LO(U1.z), le[12], m); m = fmaf(BF_HI(U1.z), le[13], m); \
    m = fmaf(BF_LO(U1.w), le[14], m); m = fmaf(BF_HI(U1.w), le[15], m);

#define EDGE_FMA16(m, A0, A1, A2, A3)                                   \
    m = fmaf(A0.x, le[ 0], m); m = fmaf(A0.y, le[ 1], m);               \
    m = fmaf(A0.z, le[ 2], m); m = fmaf(A0.w, le[ 3], m);               \
    m = fmaf(A1.x, le[ 4], m); m = fmaf(A1.y, le[ 5], m);               \
    m = fmaf(A1.z, le[ 6], m); m = fmaf(A1.w, le[ 7], m);               \
    m = fmaf(A2.x, le[ 8], m); m = fmaf(A2.y, le[ 9], m);               \
    m = fmaf(A2.z, le[10], m); m = fmaf(A2.w, le[11], m);               \
    m = fmaf(A3.x, le[12], m); m = fmaf(A3.y, le[13], m);               \
    m = fmaf(A3.z, le[14], m); m = fmaf(A3.w, le[15], m);

// ---------------- flat edge-parallel aggregation (bf16 x + bf16 edge attrs) ----------------

__global__ __launch_bounds__(256) void aggr_flat_kernel(
    const unsigned short* __restrict__ xbf, float* __restrict__ hacc,
    const int* __restrict__ srcs, const int* __restrict__ gdst,
    const unsigned int* __restrict__ gea,
    const float* __restrict__ lin_e, int layer, int E)
{
    const int lane = threadIdx.x & 63;
    float le[16];
    const float* lep = lin_e + (size_t)layer * EDIM * NDIM;
#pragma unroll
    for (int j = 0; j < EDIM; ++j) le[j] = lep[j * NDIM + lane];

    const AS4 int* sc = cs_i(srcs);
    const AS4 int* dc = cs_i(gdst);

    int w = (blockIdx.x * blockDim.x + threadIdx.x) >> 6;
    int W = (gridDim.x * blockDim.x) >> 6;
    int S = (E + W - 1) / W;
    int p    = __builtin_amdgcn_readfirstlane(w * S);
    int pend = __builtin_amdgcn_readfirstlane(min(E, p + S));
    if (p >= pend) return;

    float aggr = 0.0f;
    int dprev = dc[p];
    for (; p + 4 <= pend; p += 4) {
        int s0 = sc[p], s1 = sc[p+1], s2 = sc[p+2], s3 = sc[p+3];
        int d0 = dc[p], d1 = dc[p+1], d2 = dc[p+2], d3 = dc[p+3];
        float xs0 = bf2f(xbf[(size_t)s0 * NDIM + lane]);
        float xs1 = bf2f(xbf[(size_t)s1 * NDIM + lane]);
        float xs2 = bf2f(xbf[(size_t)s2 * NDIM + lane]);
        float xs3 = bf2f(xbf[(size_t)s3 * NDIM + lane]);
        const AS4 u32x4* ea = cs_u4(gea + (size_t)p * 8);
        u32x4 a0 = ea[0], a1 = ea[1], b0 = ea[2], b1 = ea[3];
        u32x4 c0 = ea[4], c1 = ea[5], g0 = ea[6], g1 = ea[7];
        float m0 = xs0, m1 = xs1, m2 = xs2, m3 = xs3;
        EDGE_FMA16B(m0, a0, a1)
        EDGE_FMA16B(m1, b0, b1)
        EDGE_FMA16B(m2, c0, c1)
        EDGE_FMA16B(m3, g0, g1)
        m0 = fmaxf(m0, 0.0f); m1 = fmaxf(m1, 0.0f);
        m2 = fmaxf(m2, 0.0f); m3 = fmaxf(m3, 0.0f);
        if (d3 == dprev) {                       // fast path: whole group same node
            aggr += (m0 + m1) + (m2 + m3);
        } else {                                  // boundary path (wave-uniform)
            if (d0 != dprev) { atomicAdd(&hacc[(size_t)dprev * NDIM + lane], aggr); aggr = 0.0f; dprev = d0; }
            aggr += m0;
            if (d1 != dprev) { atomicAdd(&hacc[(size_t)dprev * NDIM + lane], aggr); aggr = 0.0f; dprev = d1; }
            aggr += m1;
            if (d2 != dprev) { atomicAdd(&hacc[(size_t)dprev * NDIM + lane], aggr); aggr = 0.0f; dprev = d2; }
            aggr += m2;
            if (d3 != dprev) { atomicAdd(&hacc[(size_t)dprev * NDIM + lane], aggr); aggr = 0.0f; dprev = d3; }
            aggr += m3;
        }
    }
    for (; p < pend; ++p) {
        int s0 = sc[p];
        int d0 = dc[p];
        float xs0 = bf2f(xbf[(size_t)s0 * NDIM + lane]);
        const AS4 u32x4* ea = cs_u4(gea + (size_t)p * 8);
        u32x4 a0 = ea[0], a1 = ea[1];
        float m0 = xs0;
        EDGE_FMA16B(m0, a0, a1)
        if (d0 != dprev) { atomicAdd(&hacc[(size_t)dprev * NDIM + lane], aggr); aggr = 0.0f; dprev = d0; }
        aggr += fmaxf(m0, 0.0f);
    }
    atomicAdd(&hacc[(size_t)dprev * NDIM + lane], aggr);
}

// ---------------- MFMA MLP kernel ----------------
// v = relu(relu(h@W1+b1)@W2+b2).
// next_layer >= 0: write hnext = (1+eps_next)*v and xbf = bf16(v)  (no fp32 h write).
// next_layer <  0: write h = v in place (pooling input).

__global__ __launch_bounds__(256) void mlp_mfma_kernel(
    float* __restrict__ h,
    const float* __restrict__ W1, const float* __restrict__ b1,
    const float* __restrict__ W2, const float* __restrict__ b2,
    const float* __restrict__ eps, int next_layer,
    float* __restrict__ hnext, unsigned short* __restrict__ xbf,
    int layer, int n_nodes)
{
    __shared__ unsigned short sW1hi[4096], sW1lo[4096], sW2hi[4096], sW2lo[4096];
    __shared__ float sY[4][16 * 64];   // per-wave Y scratch, XOR-swizzled 16B granules

    const float* w1 = W1 + (size_t)layer * 4096;
    const float* w2 = W2 + (size_t)layer * 4096;
    for (int idx = threadIdx.x; idx < 4096; idx += 256) {
        int k = idx >> 6, n = idx & 63;
        int c = k >> 5, q = (k >> 3) & 3, j = k & 7;
        int fidx = ((c * 4 + q) * 64 + n) * 8 + j;
        float a = w1[idx];
        unsigned short hi = f2bf_rne(a);
        sW1hi[fidx] = hi;
        sW1lo[fidx] = f2bf_rne(a - bf2f(hi));
        float b = w2[idx];
        hi = f2bf_rne(b);
        sW2hi[fidx] = hi;
        sW2lo[fidx] = f2bf_rne(b - bf2f(hi));
    }
    __syncthreads();

    const int lane = threadIdx.x & 63;
    const int wid = threadIdx.x >> 6;
    const int m = lane & 15, q = lane >> 4;
    float* Y = sY[wid];

    const float e1n = (next_layer >= 0) ? (1.0f + eps[next_layer]) : 0.0f;

    float b1v[4], b2v[4];
#pragma unroll
    for (int nt = 0; nt < 4; ++nt) {
        b1v[nt] = b1[layer * 64 + m + nt * 16];
        b2v[nt] = b2[layer * 64 + m + nt * 16];
    }

    int tiles = (n_nodes + 15) >> 4;
    int gw = blockIdx.x * 4 + wid;
    int nw = gridDim.x * 4;
    for (int t = gw; t < tiles; t += nw) {
        int r0 = t << 4;
        int rA = r0 + m; if (rA > n_nodes - 1) rA = n_nodes - 1;
        const float* hrow = h + (size_t)rA * 64;

        short8 Ahi[2], Alo[2];
#pragma unroll
        for (int c = 0; c < 2; ++c) {
            const float4* hp = (const float4*)(hrow + c * 32 + q * 8);
            float4 v0 = hp[0], v1 = hp[1];
            cvt8(v0, v1, Ahi[c], Alo[c]);
        }

        // ---- GEMM1: Y = relu(H@W1 + b1), into swizzled LDS ----
#pragma unroll
        for (int nt = 0; nt < 4; ++nt) {
            int col = m + nt * 16;
            f32x4 acc = {0.f, 0.f, 0.f, 0.f};
#pragma unroll
            for (int c = 0; c < 2; ++c) {
                short8 bh = *(const short8*)&sW1hi[((c * 4 + q) * 64 + col) * 8];
                short8 bl = *(const short8*)&sW1lo[((c * 4 + q) * 64 + col) * 8];
                acc = __builtin_amdgcn_mfma_f32_16x16x32_bf16(Ahi[c], bh, acc, 0, 0, 0);
                acc = __builtin_amdgcn_mfma_f32_16x16x32_bf16(Alo[c], bh, acc, 0, 0, 0);
                acc = __builtin_amdgcn_mfma_f32_16x16x32_bf16(Ahi[c], bl, acc, 0, 0, 0);
            }
#pragma unroll
            for (int i = 0; i < 4; ++i) {
                int row = q * 4 + i;
                float y = fmaxf(acc[i] + b1v[nt], 0.0f);
                int gran = ((m >> 2) + 4 * nt) ^ row;     // 16B-granule XOR swizzle
                Y[(row << 6) + (gran << 2) + (m & 3)] = y;
            }
        }
        __asm__ volatile("s_waitcnt lgkmcnt(0)" ::: "memory");  // wave-internal LDS exchange

        // ---- Y -> A-fragments (hi/lo) ----
        short8 Yhi[2], Ylo[2];
#pragma unroll
        for (int c = 0; c < 2; ++c) {
            int g0 = c * 8 + q * 2;
            float4 v0 = *(const float4*)&Y[(m << 6) + ((g0 ^ m) << 2)];
            float4 v1 = *(const float4*)&Y[(m << 6) + (((g0 + 1) ^ m) << 2)];
            cvt8(v0, v1, Yhi[c], Ylo[c]);
        }

        // ---- GEMM2: out = relu(Y@W2 + b2) ----
#pragma unroll
        for (int nt = 0; nt < 4; ++nt) {
            int col = m + nt * 16;
            f32x4 acc = {0.f, 0.f, 0.f, 0.f};
#pragma unroll
            for (int c = 0; c < 2; ++c) {
                short8 bh = *(const short8*)&sW2hi[((c * 4 + q) * 64 + col) * 8];
                short8 bl = *(const short8*)&sW2lo[((c * 4 + q) * 64 + col) * 8];
                acc = __builtin_amdgcn_mfma_f32_16x16x32_bf16(Yhi[c], bh, acc, 0, 0, 0);
                acc = __builtin_amdgcn_mfma_f32_16x16x32_bf16(Ylo[c], bh, acc, 0, 0, 0);
                acc = __builtin_amdgcn_mfma_f32_16x16x32_bf16(Yhi[c], bl, acc, 0, 0, 0);
            }
#pragma unroll
            for (int i = 0; i < 4; ++i) {
                int row = r0 + q * 4 + i;
                if (row < n_nodes) {
                    float v = fmaxf(acc[i] + b2v[nt], 0.0f);
                    if (next_layer >= 0) {
                        hnext[(size_t)row * 64 + col] = e1n * v;
                        xbf[(size_t)row * 64 + col] = f2bf_rne(v);
                    } else {
                        h[(size_t)row * 64 + col] = v;
                    }
                }
            }
        }
    }
}

// fallback fused layer (eids-based) for small ws
__global__ __launch_bounds__(256) void layer_kernel(
    const float* __restrict__ xin, float* __restrict__ xout,
    const int* __restrict__ rowptr, const int* __restrict__ eids,
    const int* __restrict__ edge_index,
    const float* __restrict__ edge_attr,
    const float* __restrict__ lin_e, const float* __restrict__ W1, const float* __restrict__ b1,
    const float* __restrict__ W2, const float* __restrict__ b2, const float* __restrict__ eps,
    int layer, int n_nodes, int E)
{
    __shared__ float s_W1[NDIM * NDIM];
    __shared__ float s_W2[NDIM * NDIM];
    const float* w1 = W1 + (size_t)layer * NDIM * NDIM;
    const float* w2 = W2 + (size_t)layer * NDIM * NDIM;
    for (int i = threadIdx.x; i < NDIM * NDIM; i += 256) { s_W1[i] = w1[i]; s_W2[i] = w2[i]; }
    const int lane = threadIdx.x & 63;
    float le[16];
    const float* lep = lin_e + (size_t)layer * EDIM * NDIM;
#pragma unroll
    for (int j = 0; j < EDIM; ++j) le[j] = lep[j * NDIM + lane];
    const float bb1 = b1[layer * NDIM + lane];
    const float bb2 = b2[layer * NDIM + lane];
    const float eps1 = 1.0f + eps[layer];
    __syncthreads();
    int gw = (blockIdx.x * blockDim.x + threadIdx.x) >> 6;
    int nw = (gridDim.x * blockDim.x) >> 6;
    for (int node = gw; node < n_nodes; node += nw) {
        int p0 = rowptr[node], p1 = rowptr[node + 1];
        float aggr = 0.0f;
        for (int p = p0; p < p1; ++p) {
            int e = eids[p];
            int s = edge_index[e];
            float xs = xin[(size_t)s * NDIM + lane];
            const float4* ea = (const float4*)(edge_attr + (size_t)e * EDIM);
            float4 a0 = ea[0], a1 = ea[1], a2 = ea[2], a3 = ea[3];
            float m0 = xs;
            EDGE_FMA16(m0, a0, a1, a2, a3)
            aggr += fmaxf(m0, 0.0f);
        }
        float h = fmaf(eps1, xin[(size_t)node * NDIM + lane], aggr);
        float o1 = bb1;
#pragma unroll 8
        for (int k = 0; k < NDIM; ++k) o1 = fmaf(__shfl(h, k), s_W1[k * NDIM + lane], o1);
        o1 = fmaxf(o1, 0.0f);
        float o2 = bb2;
#pragma unroll 8
        for (int k = 0; k < NDIM; ++k) o2 = fmaf(__shfl(o1, k), s_W2[k * NDIM + lane], o2);
        xout[(size_t)node * NDIM + lane] = fmaxf(o2, 0.0f);
    }
}

// ---------------- pooling + head (atomic-free: batch is sorted) ----------------

__global__ __launch_bounds__(256) void starts_kernel(const int* __restrict__ batch,
                                                     int* __restrict__ starts, int N, int G) {
    int g = blockIdx.x * blockDim.x + threadIdx.x;
    if (g <= G) {
        int lo = 0, hi = N;
        while (lo < hi) { int mid = (lo + hi) >> 1; if (batch[mid] < g) lo = mid + 1; else hi = mid; }
        starts[g] = lo;
    }
}

__global__ __launch_bounds__(256) void poolhead_kernel(const float* __restrict__ x,
                                                       const int* __restrict__ starts,
                                                       const float* __restrict__ t_cond,
                                                       const float* __restrict__ hW1,
                                                       const float* __restrict__ hb1,
                                                       const float* __restrict__ hW2,
                                                       const float* __restrict__ hb2,
                                                       float* __restrict__ out, int G) {
    __shared__ float sW1[(NDIM + 1) * NDIM];
    __shared__ float sb1[NDIM];
    __shared__ float sW2[NDIM];
    for (int i = threadIdx.x; i < (NDIM + 1) * NDIM; i += 256) sW1[i] = hW1[i];
    if (threadIdx.x < NDIM) { sb1[threadIdx.x] = hb1[threadIdx.x]; sW2[threadIdx.x] = hW2[threadIdx.x]; }
    __syncthreads();
    const int lane = threadIdx.x & 63;
    int gw = (blockIdx.x * blockDim.x + threadIdx.x) >> 6;
    int nw = (gridDim.x * blockDim.x) >> 6;
    for (int g = gw; g < G; g += nw) {
        int a = starts[g], b = starts[g + 1];
        float s0 = 0.0f, s1 = 0.0f, s2 = 0.0f, s3 = 0.0f;
        int n = a;
        for (; n + 4 <= b; n += 4) {
            s0 += x[(size_t)n * NDIM + lane];
            s1 += x[(size_t)(n + 1) * NDIM + lane];
            s2 += x[(size_t)(n + 2) * NDIM + lane];
            s3 += x[(size_t)(n + 3) * NDIM + lane];
        }
        for (; n < b; ++n) s0 += x[(size_t)n * NDIM + lane];
        float c = fmaxf((float)(b - a), 1.0f);
        float p = ((s0 + s1) + (s2 + s3)) / c;
        float t = t_cond[g];
        float o1 = fmaf(t, sW1[NDIM * NDIM + lane], sb1[lane]);
#pragma unroll 8
        for (int k = 0; k < NDIM; ++k) o1 = fmaf(__shfl(p, k), sW1[k * NDIM + lane], o1);
        o1 = fmaxf(o1, 0.0f);
        float v = o1 * sW2[lane];
        for (int off = 32; off > 0; off >>= 1) v += __shfl_down(v, off);
        if (lane == 0) out[g] = v + hb2[0];
    }
}

// ---------------- launch ----------------

extern "C" void kernel_launch(void* const* d_in, const int* in_sizes, int n_in,
                              void* d_out, int out_size, void* d_ws, size_t ws_size,
                              hipStream_t stream) {
    const float* x_in      = (const float*)d_in[0];
    const int*   edge_index= (const int*)  d_in[1];
    const float* edge_attr = (const float*)d_in[2];
    const int*   batch     = (const int*)  d_in[3];
    const float* t_cond    = (const float*)d_in[4];
    const float* lin_e     = (const float*)d_in[5];
    const float* W1        = (const float*)d_in[6];
    const float* b1        = (const float*)d_in[7];
    const float* W2        = (const float*)d_in[8];
    const float* b2        = (const float*)d_in[9];
    const float* eps       = (const float*)d_in[10];
    const float* hW1       = (const float*)d_in[11];
    const float* hb1       = (const float*)d_in[12];
    const float* hW2       = (const float*)d_in[13];
    const float* hb2       = (const float*)d_in[14];
    float* out = (float*)d_out;

    const int N = in_sizes[3];
    const int E = in_sizes[1] / 2;
    const int G = in_sizes[4];
    const int L = in_sizes[10];
    const int ntiles = (N + SCAN_TILE - 1) / SCAN_TILE;

    char* p = (char*)d_ws;
    auto alloc = [&](size_t bytes) { char* r = p; p += (bytes + 255) & ~(size_t)255; return r; };
    int*   rowptr = (int*)  alloc((size_t)(N + 1) * 4);
    int*   fillc  = (int*)  alloc((size_t)N * 4);
    int*   srcs   = (int*)  alloc((size_t)E * 4);
    int*   gdst   = (int*)  alloc((size_t)E * 4);
    int*   tsum   = (int*)  alloc((size_t)ntiles * 4);
    int*   starts = (int*)  alloc((size_t)(G + 1) * 4);
    float* bufA   = (float*)alloc((size_t)N * NDIM * 4);
    float* bufB   = (float*)alloc((size_t)N * NDIM * 4);
    unsigned short* xbf = (unsigned short*)alloc((size_t)N * NDIM * 2);
    size_t base_used = (size_t)(p - (char*)d_ws);
    unsigned int* gea = (unsigned int*)alloc((size_t)E * 8 * 4);   // bf16-packed, 32B/edge
    bool use_gea = (base_used + (size_t)E * 8 * 4) <= ws_size
                   && (size_t)E * 4 <= (size_t)N * NDIM * 4;  // eids aliases bufA
    int* eids = (int*)bufA;   // dead after permute / fallback layer loop reads it

    // --- CSR build ---
    hipMemsetAsync(fillc, 0, (size_t)N * 4, stream);
    hist_kernel<<<(E + 255) / 256, 256, 0, stream>>>(edge_index, fillc, E);
    scan_tile_kernel<<<ntiles, SCAN_BS, 0, stream>>>(fillc, rowptr, tsum, N);
    scan_sums_kernel<<<1, 64, 0, stream>>>(tsum, ntiles);
    scan_add_kernel<<<(N + 255) / 256, 256, 0, stream>>>(rowptr, tsum, fillc, N, E);
    fill_kernel<<<(E + 255) / 256, 256, 0, stream>>>(edge_index, fillc, eids, E);
    if (use_gea) {
        permute_kernel<<<(E + 255) / 256, 256, 0, stream>>>(eids, edge_index, (const float4*)edge_attr,
                                                            (u32x4*)gea, srcs, gdst, E);
    }
    starts_kernel<<<(G + 256) / 256, 256, 0, stream>>>(batch, starts, N, G);

    // --- 4 GINEConv layers ---
    const int n4 = N * NDIM / 4;
    if (use_gea) {
        float* hacc  = bufA;   // init overwrites eids (dead after permute)
        float* other = bufB;
        init_kernel<<<2048, 256, 0, stream>>>((const float4*)x_in, (float4*)hacc, xbf, eps, n4);
        for (int l = 0; l < L; ++l) {
            aggr_flat_kernel<<<2048, 256, 0, stream>>>(xbf, hacc, srcs, gdst, gea, lin_e, l, E);
            int nl = (l + 1 < L) ? l + 1 : -1;
            mlp_mfma_kernel<<<1024, 256, 0, stream>>>(hacc, W1, b1, W2, b2,
                                                      eps, nl, other, xbf, l, N);
            if (nl >= 0) { float* t = hacc; hacc = other; other = t; }
        }
        // final layer wrote hacc in place
        poolhead_kernel<<<512, 256, 0, stream>>>(hacc, starts, t_cond, hW1, hb1, hW2, hb2, out, G);
    } else {
        const float* cur = x_in;
        float* work = bufB;   // eids aliases bufA; avoid bufA as first target
        for (int l = 0; l < L; ++l) {
            float* tgt = (l == 0) ? bufB : work;
            layer_kernel<<<1024, 256, 0, stream>>>(cur, tgt, rowptr, eids, edge_index,
                                                   edge_attr, lin_e, W1, b1, W2, b2, eps, l, N, E);
            cur = tgt;
            work = (tgt == bufA) ? bufB : bufA;
        }
        poolhead_kernel<<<512, 256, 0, stream>>>(cur, starts, t_cond, hW1, hb1, hW2, hb2, out, G);
    }
}

// Round 10
// 612.344 us; speedup vs baseline: 1.1252x; 1.1252x over previous
//
#include <hip/hip_runtime.h>

#define NDIM 64
#define EDIM 16
#define SCAN_BS 256
#define SCAN_TILE 2048   // SCAN_BS * 8
#define BSHIFT 9         // bucket = 512 consecutive dst nodes
#define NB_MAX 256
#define P1_TILE 4096
#define P2_CAP 8192

typedef __attribute__((ext_vector_type(8))) short short8;   // 8 x bf16 (4 VGPR)
typedef __attribute__((ext_vector_type(4))) float f32x4;    // MFMA acc
typedef __attribute__((ext_vector_type(4))) unsigned int u32x4;

// ---------------- scalar (constant AS) load helpers ----------------
#define AS4 __attribute__((address_space(4)))
__device__ inline const AS4 int* cs_i(const int* p) {
    return (const AS4 int*)(unsigned long long)p;
}
__device__ inline const AS4 u32x4* cs_u4(const unsigned int* p) {
    return (const AS4 u32x4*)(unsigned long long)p;
}

// exact bf16->fp32 reconstruction (scalar-pipe friendly: shift / and)
#define BF_LO(u) __uint_as_float((u) << 16)
#define BF_HI(u) __uint_as_float((u) & 0xffff0000u)

// ---------------- bf16 helpers ----------------
__device__ inline unsigned short f2bf_rne(float f) {
    unsigned int u = __float_as_uint(f);
    unsigned int r = u + 0x7FFFu + ((u >> 16) & 1u);
    return (unsigned short)(r >> 16);
}
__device__ inline float bf2f(unsigned short h) {
    return __uint_as_float(((unsigned int)h) << 16);
}
__device__ inline unsigned int pack2(float a, float b) {
    return (unsigned int)f2bf_rne(a) | ((unsigned int)f2bf_rne(b) << 16);
}
__device__ inline void cvt8(const float4 v0, const float4 v1, short8& hi, short8& lo) {
    float v[8] = {v0.x, v0.y, v0.z, v0.w, v1.x, v1.y, v1.z, v1.w};
#pragma unroll
    for (int j = 0; j < 8; ++j) {
        unsigned short h = f2bf_rne(v[j]);
        hi[j] = (short)h;
        lo[j] = (short)f2bf_rne(v[j] - bf2f(h));
    }
}

// ---------------- two-level bucket sort (replaces node-level counting sort) ----------------
// Rationale (r7-r9 evidence): node-granular scatter = 1M random 4B writes over
// 100k COLD cursor lines -> 75MB write-allocate traffic, 86us, nt-store no help.
// Bucketing by dst>>9 keeps only 196 hot frontier regions -> allocate amortized.

__global__ __launch_bounds__(256) void bucket_hist_kernel(const int* __restrict__ edge_index,
                                                          int* __restrict__ bhist, int E, int NB) {
    __shared__ int lh[NB_MAX];
    for (int i = threadIdx.x; i < NB; i += 256) lh[i] = 0;
    __syncthreads();
    int base = blockIdx.x * P1_TILE;
    for (int i = threadIdx.x; i < P1_TILE; i += 256) {
        int e = base + i;
        if (e < E) atomicAdd(&lh[edge_index[E + e] >> BSHIFT], 1);
    }
    __syncthreads();
    for (int i = threadIdx.x; i < NB; i += 256) if (lh[i]) atomicAdd(&bhist[i], lh[i]);
}

__global__ void bucket_scan_kernel(const int* __restrict__ bhist,
                                   int* __restrict__ boff, int* __restrict__ bcur, int NB) {
    if (threadIdx.x == 0 && blockIdx.x == 0) {
        int run = 0;
        for (int i = 0; i < NB; ++i) { boff[i] = run; bcur[i] = run; run += bhist[i]; }
        boff[NB] = run;
    }
}

__global__ __launch_bounds__(256) void bucket_scatter_kernel(const int* __restrict__ edge_index,
                                                             int* __restrict__ bcur,
                                                             int* __restrict__ eids, int E, int NB) {
    __shared__ int lh[NB_MAX];
    __shared__ int lbase[NB_MAX];
    for (int i = threadIdx.x; i < NB; i += 256) lh[i] = 0;
    __syncthreads();
    int base = blockIdx.x * P1_TILE;
    for (int i = threadIdx.x; i < P1_TILE; i += 256) {
        int e = base + i;
        if (e < E) atomicAdd(&lh[edge_index[E + e] >> BSHIFT], 1);
    }
    __syncthreads();
    for (int i = threadIdx.x; i < NB; i += 256) {
        int c = lh[i];
        lbase[i] = c ? atomicAdd(&bcur[i], c) : 0;   // reserve contiguous run per (block,bucket)
    }
    __syncthreads();
    for (int i = threadIdx.x; i < NB; i += 256) lh[i] = 0;
    __syncthreads();
    for (int i = threadIdx.x; i < P1_TILE; i += 256) {
        int e = base + i;
        if (e < E) {
            int cb = edge_index[E + e] >> BSHIFT;
            int pos = lbase[cb] + atomicAdd(&lh[cb], 1);
            eids[pos] = e;
        }
    }
}

// one block per bucket: LDS counting sort on the 9 low dst bits.
// Writes sorted eids (in place) + gdst. Traffic confined to the bucket's
// ~20-40KB region (L2-hot). Overflow (n > P2_CAP) left unsorted — still
// correct: aggr_flat flushes on every dst change regardless of order.
__global__ __launch_bounds__(256) void bucket_sort_kernel(const int* __restrict__ edge_index,
                                                          int* __restrict__ eids,
                                                          int* __restrict__ gdst,
                                                          const int* __restrict__ boff, int E) {
    __shared__ int leids[P2_CAP];
    __shared__ unsigned short lloc[P2_CAP];
    __shared__ int cnt[512];
    __shared__ int offs[512];
    int b = blockIdx.x;
    int base = boff[b], n = boff[b + 1] - base;
    int node0 = b << BSHIFT;
    int nproc = min(n, P2_CAP);
    for (int i = threadIdx.x; i < 512; i += 256) cnt[i] = 0;
    __syncthreads();
    for (int i = threadIdx.x; i < nproc; i += 256) {
        int e = eids[base + i];
        leids[i] = e;
        int loc = edge_index[E + e] - node0;
        lloc[i] = (unsigned short)loc;
        atomicAdd(&cnt[loc], 1);
    }
    __syncthreads();
    if (threadIdx.x == 0) {
        int run = 0;
        for (int i = 0; i < 512; ++i) { offs[i] = run; run += cnt[i]; }
    }
    __syncthreads();
    for (int i = threadIdx.x; i < 512; i += 256) cnt[i] = 0;
    __syncthreads();
    for (int i = threadIdx.x; i < nproc; i += 256) {
        int loc = lloc[i];
        int pos = offs[loc] + atomicAdd(&cnt[loc], 1);
        eids[base + pos] = leids[i];
        gdst[base + pos] = node0 + loc;
    }
    for (int i = P2_CAP + threadIdx.x; i < n; i += 256) {   // overflow remainder
        int e = eids[base + i];
        gdst[base + i] = edge_index[E + e];
    }
}

// ---------------- legacy node-level CSR build (fallback path only) ----------------

__global__ __launch_bounds__(256) void hist_kernel(const int* __restrict__ edge_index,
                                                   int* __restrict__ deg, int E) {
    int e = blockIdx.x * blockDim.x + threadIdx.x;
    if (e < E) atomicAdd(&deg[edge_index[E + e]], 1);
}

__global__ __launch_bounds__(SCAN_BS) void scan_tile_kernel(const int* __restrict__ deg,
                                                            int* __restrict__ excl,
                                                            int* __restrict__ tsum, int n) {
    __shared__ int sdata[SCAN_BS];
    int base = blockIdx.x * SCAN_TILE + threadIdx.x * 8;
    int v[8]; int s = 0;
#pragma unroll
    for (int j = 0; j < 8; ++j) { int idx = base + j; int val = (idx < n) ? deg[idx] : 0; v[j] = val; s += val; }
    sdata[threadIdx.x] = s;
    __syncthreads();
    for (int off = 1; off < SCAN_BS; off <<= 1) {
        int t = (threadIdx.x >= (unsigned)off) ? sdata[threadIdx.x - off] : 0;
        __syncthreads();
        sdata[threadIdx.x] += t;
        __syncthreads();
    }
    int incl = sdata[threadIdx.x];
    if (threadIdx.x == SCAN_BS - 1) tsum[blockIdx.x] = incl;
    int run = incl - s;
#pragma unroll
    for (int j = 0; j < 8; ++j) { int idx = base + j; if (idx < n) excl[idx] = run; run += v[j]; }
}

__global__ void scan_sums_kernel(int* tsum, int ntiles) {
    if (threadIdx.x == 0 && blockIdx.x == 0) {
        int run = 0;
        for (int i = 0; i < ntiles; ++i) { int t = tsum[i]; tsum[i] = run; run += t; }
    }
}

__global__ __launch_bounds__(256) void scan_add_kernel(int* __restrict__ rowptr,
                                                       const int* __restrict__ tsum,
                                                       int* __restrict__ fillc, int n, int E) {
    int i = blockIdx.x * blockDim.x + threadIdx.x;
    if (i < n) {
        int v = rowptr[i] + tsum[i / SCAN_TILE];
        rowptr[i] = v;
        fillc[i] = v;
    }
    if (i == 0) rowptr[n] = E;
}

__global__ __launch_bounds__(256) void fill_kernel(const int* __restrict__ edge_index,
                                                   int* __restrict__ fillc,
                                                   int* __restrict__ eids, int E) {
    int e = blockIdx.x * blockDim.x + threadIdx.x;
    if (e < E) {
        int d = edge_index[E + e];
        int pos = atomicAdd(&fillc[d], 1);
        eids[pos] = e;
    }
}

// gather-style permute: coalesced eids read; random reads (L2/L3-resident);
// writes (gea bf16-packed, srcs, gdst) fully coalesced. gdst write is
// redundant with bucket_sort (same values) but kept for the fallback build.
__global__ __launch_bounds__(256) void permute_kernel(const int* __restrict__ eids,
                                                      const int* __restrict__ edge_index,
                                                      const float4* __restrict__ ea,
                                                      u32x4* __restrict__ gea,
                                                      int* __restrict__ srcs,
                                                      int* __restrict__ gdst, int E) {
    int p = blockIdx.x * blockDim.x + threadIdx.x;
    if (p < E) {
        int e = eids[p];
        srcs[p] = edge_index[e];
        gdst[p] = edge_index[E + e];
        float4 r0 = ea[(size_t)e*4+0], r1 = ea[(size_t)e*4+1],
               r2 = ea[(size_t)e*4+2], r3 = ea[(size_t)e*4+3];
        u32x4 d0, d1;
        d0.x = pack2(r0.x, r0.y); d0.y = pack2(r0.z, r0.w);
        d0.z = pack2(r1.x, r1.y); d0.w = pack2(r1.z, r1.w);
        d1.x = pack2(r2.x, r2.y); d1.y = pack2(r2.z, r2.w);
        d1.z = pack2(r3.x, r3.y); d1.w = pack2(r3.z, r3.w);
        gea[(size_t)p*2+0] = d0; gea[(size_t)p*2+1] = d1;
    }
}

// layer-0 init: hacc = (1+eps0)*x (fp32) and xbf = bf16(x)
__global__ __launch_bounds__(256) void init_kernel(const float4* __restrict__ x,
                                                   float4* __restrict__ h,
                                                   unsigned short* __restrict__ xbf,
                                                   const float* __restrict__ eps, int n4) {
    float e1 = 1.0f + eps[0];
    int i = blockIdx.x * blockDim.x + threadIdx.x;
    int stride = gridDim.x * blockDim.x;
    for (; i < n4; i += stride) {
        float4 v = x[i];
        uint2 u;
        u.x = pack2(v.x, v.y);
        u.y = pack2(v.z, v.w);
        *(uint2*)(xbf + (size_t)i * 4) = u;
        v.x *= e1; v.y *= e1; v.z *= e1; v.w *= e1;
        h[i] = v;
    }
}

// 16 fma with bf16-packed edge attrs (U0,U1 = 8 dwords); unpack is exact.
#define EDGE_FMA16B(m, U0, U1)                                          \
    m = fmaf(BF_LO(U0.x), le[ 0], m); m = fmaf(BF_HI(U0.x), le[ 1], m); \
    m = fmaf(BF_LO(U0.y), le[ 2], m); m = fmaf(BF_HI(U0.y), le[ 3], m); \
    m = fmaf(BF_LO(U0.z), le[ 4], m); m = fmaf(BF_HI(U0.z), le[ 5], m); \
    m = fmaf(BF_LO(U0.w), le[ 6], m); m = fmaf(BF_HI(U0.w), le[ 7], m); \
    m = fmaf(BF_LO(U1.x), le[ 8], m); m = fmaf(BF_HI(U1.x), le[ 9], m); \
    m = fmaf(BF_LO(U1.y), le[10], m); m = fmaf(BF_HI(U1.y), le[11], m); \
    m = fmaf(BF_LO(U1.z), le[12], m); m = fmaf(BF_HI(U1.z), le[13], m); \
    m = fmaf(BF_LO(U1.w), le[14], m); m = fmaf(BF_HI(U1.w), le[15], m);

#define EDGE_FMA16(m, A0, A1, A2, A3)                                   \
    m = fmaf(A0.x, le[ 0], m); m = fmaf(A0.y, le[ 1], m);               \
    m = fmaf(A0.z, le[ 2], m); m = fmaf(A0.w, le[ 3], m);               \
    m = fmaf(A1.x, le[ 4], m); m = fmaf(A1.y, le[ 5], m);               \
    m = fmaf(A1.z, le[ 6], m); m = fmaf(A1.w, le[ 7], m);               \
    m = fmaf(A2.x, le[ 8], m); m = fmaf(A2.y, le[ 9], m);               \
    m = fmaf(A2.z, le[10], m); m = fmaf(A2.w, le[11], m);               \
    m = fmaf(A3.x, le[12], m); m = fmaf(A3.y, le[13], m);               \
    m = fmaf(A3.z, le[14], m); m = fmaf(A3.w, le[15], m);

// ---------------- flat edge-parallel aggregation (bf16 x + bf16 edge attrs) ----------------

__global__ __launch_bounds__(256) void aggr_flat_kernel(
    const unsigned short* __restrict__ xbf, float* __restrict__ hacc,
    const int* __restrict__ srcs, const int* __restrict__ gdst,
    const unsigned int* __restrict__ gea,
    const float* __restrict__ lin_e, int layer, int E)
{
    const int lane = threadIdx.x & 63;
    float le[16];
    const float* lep = lin_e + (size_t)layer * EDIM * NDIM;
#pragma unroll
    for (int j = 0; j < EDIM; ++j) le[j] = lep[j * NDIM + lane];

    const AS4 int* sc = cs_i(srcs);
    const AS4 int* dc = cs_i(gdst);

    int w = (blockIdx.x * blockDim.x + threadIdx.x) >> 6;
    int W = (gridDim.x * blockDim.x) >> 6;
    int S = (E + W - 1) / W;
    int p    = __builtin_amdgcn_readfirstlane(w * S);
    int pend = __builtin_amdgcn_readfirstlane(min(E, p + S));
    if (p >= pend) return;

    float aggr = 0.0f;
    int dprev = dc[p];
    for (; p + 4 <= pend; p += 4) {
        int s0 = sc[p], s1 = sc[p+1], s2 = sc[p+2], s3 = sc[p+3];
        int d0 = dc[p], d1 = dc[p+1], d2 = dc[p+2], d3 = dc[p+3];
        float xs0 = bf2f(xbf[(size_t)s0 * NDIM + lane]);
        float xs1 = bf2f(xbf[(size_t)s1 * NDIM + lane]);
        float xs2 = bf2f(xbf[(size_t)s2 * NDIM + lane]);
        float xs3 = bf2f(xbf[(size_t)s3 * NDIM + lane]);
        const AS4 u32x4* ea = cs_u4(gea + (size_t)p * 8);
        u32x4 a0 = ea[0], a1 = ea[1], b0 = ea[2], b1 = ea[3];
        u32x4 c0 = ea[4], c1 = ea[5], g0 = ea[6], g1 = ea[7];
        float m0 = xs0, m1 = xs1, m2 = xs2, m3 = xs3;
        EDGE_FMA16B(m0, a0, a1)
        EDGE_FMA16B(m1, b0, b1)
        EDGE_FMA16B(m2, c0, c1)
        EDGE_FMA16B(m3, g0, g1)
        m0 = fmaxf(m0, 0.0f); m1 = fmaxf(m1, 0.0f);
        m2 = fmaxf(m2, 0.0f); m3 = fmaxf(m3, 0.0f);
        if (d3 == dprev) {                       // fast path: whole group same node
            aggr += (m0 + m1) + (m2 + m3);
        } else {                                  // boundary path (wave-uniform)
            if (d0 != dprev) { atomicAdd(&hacc[(size_t)dprev * NDIM + lane], aggr); aggr = 0.0f; dprev = d0; }
            aggr += m0;
            if (d1 != dprev) { atomicAdd(&hacc[(size_t)dprev * NDIM + lane], aggr); aggr = 0.0f; dprev = d1; }
            aggr += m1;
            if (d2 != dprev) { atomicAdd(&hacc[(size_t)dprev * NDIM + lane], aggr); aggr = 0.0f; dprev = d2; }
            aggr += m2;
            if (d3 != dprev) { atomicAdd(&hacc[(size_t)dprev * NDIM + lane], aggr); aggr = 0.0f; dprev = d3; }
            aggr += m3;
        }
    }
    for (; p < pend; ++p) {
        int s0 = sc[p];
        int d0 = dc[p];
        float xs0 = bf2f(xbf[(size_t)s0 * NDIM + lane]);
        const AS4 u32x4* ea = cs_u4(gea + (size_t)p * 8);
        u32x4 a0 = ea[0], a1 = ea[1];
        float m0 = xs0;
        EDGE_FMA16B(m0, a0, a1)
        if (d0 != dprev) { atomicAdd(&hacc[(size_t)dprev * NDIM + lane], aggr); aggr = 0.0f; dprev = d0; }
        aggr += fmaxf(m0, 0.0f);
    }
    atomicAdd(&hacc[(size_t)dprev * NDIM + lane], aggr);
}

// ---------------- MFMA MLP kernel ----------------
// v = relu(relu(h@W1+b1)@W2+b2).
// next_layer >= 0: write hnext = (1+eps_next)*v and xbf = bf16(v).
// next_layer <  0: write h = v in place (pooling input).

__global__ __launch_bounds__(256) void mlp_mfma_kernel(
    float* __restrict__ h,
    const float* __restrict__ W1, const float* __restrict__ b1,
    const float* __restrict__ W2, const float* __restrict__ b2,
    const float* __restrict__ eps, int next_layer,
    float* __restrict__ hnext, unsigned short* __restrict__ xbf,
    int layer, int n_nodes)
{
    __shared__ unsigned short sW1hi[4096], sW1lo[4096], sW2hi[4096], sW2lo[4096];
    __shared__ float sY[4][16 * 64];   // per-wave Y scratch, XOR-swizzled 16B granules

    const float* w1 = W1 + (size_t)layer * 4096;
    const float* w2 = W2 + (size_t)layer * 4096;
    for (int idx = threadIdx.x; idx < 4096; idx += 256) {
        int k = idx >> 6, n = idx & 63;
        int c = k >> 5, q = (k >> 3) & 3, j = k & 7;
        int fidx = ((c * 4 + q) * 64 + n) * 8 + j;
        float a = w1[idx];
        unsigned short hi = f2bf_rne(a);
        sW1hi[fidx] = hi;
        sW1lo[fidx] = f2bf_rne(a - bf2f(hi));
        float b = w2[idx];
        hi = f2bf_rne(b);
        sW2hi[fidx] = hi;
        sW2lo[fidx] = f2bf_rne(b - bf2f(hi));
    }
    __syncthreads();

    const int lane = threadIdx.x & 63;
    const int wid = threadIdx.x >> 6;
    const int m = lane & 15, q = lane >> 4;
    float* Y = sY[wid];

    const float e1n = (next_layer >= 0) ? (1.0f + eps[next_layer]) : 0.0f;

    float b1v[4], b2v[4];
#pragma unroll
    for (int nt = 0; nt < 4; ++nt) {
        b1v[nt] = b1[layer * 64 + m + nt * 16];
        b2v[nt] = b2[layer * 64 + m + nt * 16];
    }

    int tiles = (n_nodes + 15) >> 4;
    int gw = blockIdx.x * 4 + wid;
    int nw = gridDim.x * 4;
    for (int t = gw; t < tiles; t += nw) {
        int r0 = t << 4;
        int rA = r0 + m; if (rA > n_nodes - 1) rA = n_nodes - 1;
        const float* hrow = h + (size_t)rA * 64;

        short8 Ahi[2], Alo[2];
#pragma unroll
        for (int c = 0; c < 2; ++c) {
            const float4* hp = (const float4*)(hrow + c * 32 + q * 8);
            float4 v0 = hp[0], v1 = hp[1];
            cvt8(v0, v1, Ahi[c], Alo[c]);
        }

        // ---- GEMM1: Y = relu(H@W1 + b1), into swizzled LDS ----
#pragma unroll
        for (int nt = 0; nt < 4; ++nt) {
            int col = m + nt * 16;
            f32x4 acc = {0.f, 0.f, 0.f, 0.f};
#pragma unroll
            for (int c = 0; c < 2; ++c) {
                short8 bh = *(const short8*)&sW1hi[((c * 4 + q) * 64 + col) * 8];
                short8 bl = *(const short8*)&sW1lo[((c * 4 + q) * 64 + col) * 8];
                acc = __builtin_amdgcn_mfma_f32_16x16x32_bf16(Ahi[c], bh, acc, 0, 0, 0);
                acc = __builtin_amdgcn_mfma_f32_16x16x32_bf16(Alo[c], bh, acc, 0, 0, 0);
                acc = __builtin_amdgcn_mfma_f32_16x16x32_bf16(Ahi[c], bl, acc, 0, 0, 0);
            }
#pragma unroll
            for (int i = 0; i < 4; ++i) {
                int row = q * 4 + i;
                float y = fmaxf(acc[i] + b1v[nt], 0.0f);
                int gran = ((m >> 2) + 4 * nt) ^ row;     // 16B-granule XOR swizzle
                Y[(row << 6) + (gran << 2) + (m & 3)] = y;
            }
        }
        __asm__ volatile("s_waitcnt lgkmcnt(0)" ::: "memory");  // wave-internal LDS exchange

        // ---- Y -> A-fragments (hi/lo) ----
        short8 Yhi[2], Ylo[2];
#pragma unroll
        for (int c = 0; c < 2; ++c) {
            int g0 = c * 8 + q * 2;
            float4 v0 = *(const float4*)&Y[(m << 6) + ((g0 ^ m) << 2)];
            float4 v1 = *(const float4*)&Y[(m << 6) + (((g0 + 1) ^ m) << 2)];
            cvt8(v0, v1, Yhi[c], Ylo[c]);
        }

        // ---- GEMM2: out = relu(Y@W2 + b2) ----
#pragma unroll
        for (int nt = 0; nt < 4; ++nt) {
            int col = m + nt * 16;
            f32x4 acc = {0.f, 0.f, 0.f, 0.f};
#pragma unroll
            for (int c = 0; c < 2; ++c) {
                short8 bh = *(const short8*)&sW2hi[((c * 4 + q) * 64 + col) * 8];
                short8 bl = *(const short8*)&sW2lo[((c * 4 + q) * 64 + col) * 8];
                acc = __builtin_amdgcn_mfma_f32_16x16x32_bf16(Yhi[c], bh, acc, 0, 0, 0);
                acc = __builtin_amdgcn_mfma_f32_16x16x32_bf16(Ylo[c], bh, acc, 0, 0, 0);
                acc = __builtin_amdgcn_mfma_f32_16x16x32_bf16(Yhi[c], bl, acc, 0, 0, 0);
            }
#pragma unroll
            for (int i = 0; i < 4; ++i) {
                int row = r0 + q * 4 + i;
                if (row < n_nodes) {
                    float v = fmaxf(acc[i] + b2v[nt], 0.0f);
                    if (next_layer >= 0) {
                        hnext[(size_t)row * 64 + col] = e1n * v;
                        xbf[(size_t)row * 64 + col] = f2bf_rne(v);
                    } else {
                        h[(size_t)row * 64 + col] = v;
                    }
                }
            }
        }
    }
}

// fallback fused layer (eids-based) for small ws
__global__ __launch_bounds__(256) void layer_kernel(
    const float* __restrict__ xin, float* __restrict__ xout,
    const int* __restrict__ rowptr, const int* __restrict__ eids,
    const int* __restrict__ edge_index,
    const float* __restrict__ edge_attr,
    const float* __restrict__ lin_e, const float* __restrict__ W1, const float* __restrict__ b1,
    const float* __restrict__ W2, const float* __restrict__ b2, const float* __restrict__ eps,
    int layer, int n_nodes, int E)
{
    __shared__ float s_W1[NDIM * NDIM];
    __shared__ float s_W2[NDIM * NDIM];
    const float* w1 = W1 + (size_t)layer * NDIM * NDIM;
    const float* w2 = W2 + (size_t)layer * NDIM * NDIM;
    for (int i = threadIdx.x; i < NDIM * NDIM; i += 256) { s_W1[i] = w1[i]; s_W2[i] = w2[i]; }
    const int lane = threadIdx.x & 63;
    float le[16];
    const float* lep = lin_e + (size_t)layer * EDIM * NDIM;
#pragma unroll
    for (int j = 0; j < EDIM; ++j) le[j] = lep[j * NDIM + lane];
    const float bb1 = b1[layer * NDIM + lane];
    const float bb2 = b2[layer * NDIM + lane];
    const float eps1 = 1.0f + eps[layer];
    __syncthreads();
    int gw = (blockIdx.x * blockDim.x + threadIdx.x) >> 6;
    int nw = (gridDim.x * blockDim.x) >> 6;
    for (int node = gw; node < n_nodes; node += nw) {
        int p0 = rowptr[node], p1 = rowptr[node + 1];
        float aggr = 0.0f;
        for (int p = p0; p < p1; ++p) {
            int e = eids[p];
            int s = edge_index[e];
            float xs = xin[(size_t)s * NDIM + lane];
            const float4* ea = (const float4*)(edge_attr + (size_t)e * EDIM);
            float4 a0 = ea[0], a1 = ea[1], a2 = ea[2], a3 = ea[3];
            float m0 = xs;
            EDGE_FMA16(m0, a0, a1, a2, a3)
            aggr += fmaxf(m0, 0.0f);
        }
        float h = fmaf(eps1, xin[(size_t)node * NDIM + lane], aggr);
        float o1 = bb1;
#pragma unroll 8
        for (int k = 0; k < NDIM; ++k) o1 = fmaf(__shfl(h, k), s_W1[k * NDIM + lane], o1);
        o1 = fmaxf(o1, 0.0f);
        float o2 = bb2;
#pragma unroll 8
        for (int k = 0; k < NDIM; ++k) o2 = fmaf(__shfl(o1, k), s_W2[k * NDIM + lane], o2);
        xout[(size_t)node * NDIM + lane] = fmaxf(o2, 0.0f);
    }
}

// ---------------- pooling + head (atomic-free: batch is sorted) ----------------

__global__ __launch_bounds__(256) void starts_kernel(const int* __restrict__ batch,
                                                     int* __restrict__ starts, int N, int G) {
    int g = blockIdx.x * blockDim.x + threadIdx.x;
    if (g <= G) {
        int lo = 0, hi = N;
        while (lo < hi) { int mid = (lo + hi) >> 1; if (batch[mid] < g) lo = mid + 1; else hi = mid; }
        starts[g] = lo;
    }
}

__global__ __launch_bounds__(256) void poolhead_kernel(const float* __restrict__ x,
                                                       const int* __restrict__ starts,
                                                       const float* __restrict__ t_cond,
                                                       const float* __restrict__ hW1,
                                                       const float* __restrict__ hb1,
                                                       const float* __restrict__ hW2,
                                                       const float* __restrict__ hb2,
                                                       float* __restrict__ out, int G) {
    __shared__ float sW1[(NDIM + 1) * NDIM];
    __shared__ float sb1[NDIM];
    __shared__ float sW2[NDIM];
    for (int i = threadIdx.x; i < (NDIM + 1) * NDIM; i += 256) sW1[i] = hW1[i];
    if (threadIdx.x < NDIM) { sb1[threadIdx.x] = hb1[threadIdx.x]; sW2[threadIdx.x] = hW2[threadIdx.x]; }
    __syncthreads();
    const int lane = threadIdx.x & 63;
    int gw = (blockIdx.x * blockDim.x + threadIdx.x) >> 6;
    int nw = (gridDim.x * blockDim.x) >> 6;
    for (int g = gw; g < G; g += nw) {
        int a = starts[g], b = starts[g + 1];
        float s0 = 0.0f, s1 = 0.0f, s2 = 0.0f, s3 = 0.0f;
        int n = a;
        for (; n + 4 <= b; n += 4) {
            s0 += x[(size_t)n * NDIM + lane];
            s1 += x[(size_t)(n + 1) * NDIM + lane];
            s2 += x[(size_t)(n + 2) * NDIM + lane];
            s3 += x[(size_t)(n + 3) * NDIM + lane];
        }
        for (; n < b; ++n) s0 += x[(size_t)n * NDIM + lane];
        float c = fmaxf((float)(b - a), 1.0f);
        float p = ((s0 + s1) + (s2 + s3)) / c;
        float t = t_cond[g];
        float o1 = fmaf(t, sW1[NDIM * NDIM + lane], sb1[lane]);
#pragma unroll 8
        for (int k = 0; k < NDIM; ++k) o1 = fmaf(__shfl(p, k), sW1[k * NDIM + lane], o1);
        o1 = fmaxf(o1, 0.0f);
        float v = o1 * sW2[lane];
        for (int off = 32; off > 0; off >>= 1) v += __shfl_down(v, off);
        if (lane == 0) out[g] = v + hb2[0];
    }
}

// ---------------- launch ----------------

extern "C" void kernel_launch(void* const* d_in, const int* in_sizes, int n_in,
                              void* d_out, int out_size, void* d_ws, size_t ws_size,
                              hipStream_t stream) {
    const float* x_in      = (const float*)d_in[0];
    const int*   edge_index= (const int*)  d_in[1];
    const float* edge_attr = (const float*)d_in[2];
    const int*   batch     = (const int*)  d_in[3];
    const float* t_cond    = (const float*)d_in[4];
    const float* lin_e     = (const float*)d_in[5];
    const float* W1        = (const float*)d_in[6];
    const float* b1        = (const float*)d_in[7];
    const float* W2        = (const float*)d_in[8];
    const float* b2        = (const float*)d_in[9];
    const float* eps       = (const float*)d_in[10];
    const float* hW1       = (const float*)d_in[11];
    const float* hb1       = (const float*)d_in[12];
    const float* hW2       = (const float*)d_in[13];
    const float* hb2       = (const float*)d_in[14];
    float* out = (float*)d_out;

    const int N = in_sizes[3];
    const int E = in_sizes[1] / 2;
    const int G = in_sizes[4];
    const int L = in_sizes[10];
    const int ntiles = (N + SCAN_TILE - 1) / SCAN_TILE;
    const int NB = (N + (1 << BSHIFT) - 1) >> BSHIFT;

    char* p = (char*)d_ws;
    auto alloc = [&](size_t bytes) { char* r = p; p += (bytes + 255) & ~(size_t)255; return r; };
    int*   rowptr = (int*)  alloc((size_t)(N + 1) * 4);   // fallback only
    int*   fillc  = (int*)  alloc((size_t)N * 4);         // fallback only
    int*   srcs   = (int*)  alloc((size_t)E * 4);
    int*   gdst   = (int*)  alloc((size_t)E * 4);
    int*   tsum   = (int*)  alloc((size_t)ntiles * 4);
    int*   bhist  = (int*)  alloc((size_t)NB * 4);
    int*   boff   = (int*)  alloc((size_t)(NB + 1) * 4);
    int*   bcur   = (int*)  alloc((size_t)NB * 4);
    int*   starts = (int*)  alloc((size_t)(G + 1) * 4);
    float* bufA   = (float*)alloc((size_t)N * NDIM * 4);
    float* bufB   = (float*)alloc((size_t)N * NDIM * 4);
    unsigned short* xbf = (unsigned short*)alloc((size_t)N * NDIM * 2);
    size_t base_used = (size_t)(p - (char*)d_ws);
    unsigned int* gea = (unsigned int*)alloc((size_t)E * 8 * 4);   // bf16-packed, 32B/edge
    bool use_gea = (base_used + (size_t)E * 8 * 4) <= ws_size
                   && (size_t)E * 4 <= (size_t)N * NDIM * 4;  // eids aliases bufA
    bool fast_sort = use_gea && (NB <= NB_MAX);
    int* eids = (int*)bufA;   // dead after permute

    const int p1_blocks = (E + P1_TILE - 1) / P1_TILE;

    // --- edge sort (dst-ordered) ---
    if (fast_sort) {
        hipMemsetAsync(bhist, 0, (size_t)NB * 4, stream);
        bucket_hist_kernel<<<p1_blocks, 256, 0, stream>>>(edge_index, bhist, E, NB);
        bucket_scan_kernel<<<1, 64, 0, stream>>>(bhist, boff, bcur, NB);
        bucket_scatter_kernel<<<p1_blocks, 256, 0, stream>>>(edge_index, bcur, eids, E, NB);
        bucket_sort_kernel<<<NB, 256, 0, stream>>>(edge_index, eids, gdst, boff, E);
    } else {
        hipMemsetAsync(fillc, 0, (size_t)N * 4, stream);
        hist_kernel<<<(E + 255) / 256, 256, 0, stream>>>(edge_index, fillc, E);
        scan_tile_kernel<<<ntiles, SCAN_BS, 0, stream>>>(fillc, rowptr, tsum, N);
        scan_sums_kernel<<<1, 64, 0, stream>>>(tsum, ntiles);
        scan_add_kernel<<<(N + 255) / 256, 256, 0, stream>>>(rowptr, tsum, fillc, N, E);
        fill_kernel<<<(E + 255) / 256, 256, 0, stream>>>(edge_index, fillc, eids, E);
    }
    if (use_gea) {
        permute_kernel<<<(E + 255) / 256, 256, 0, stream>>>(eids, edge_index, (const float4*)edge_attr,
                                                            (u32x4*)gea, srcs, gdst, E);
    }
    starts_kernel<<<(G + 256) / 256, 256, 0, stream>>>(batch, starts, N, G);

    // --- 4 GINEConv layers ---
    const int n4 = N * NDIM / 4;
    if (use_gea) {
        float* hacc  = bufA;   // init overwrites eids (dead after permute)
        float* other = bufB;
        init_kernel<<<2048, 256, 0, stream>>>((const float4*)x_in, (float4*)hacc, xbf, eps, n4);
        for (int l = 0; l < L; ++l) {
            aggr_flat_kernel<<<2048, 256, 0, stream>>>(xbf, hacc, srcs, gdst, gea, lin_e, l, E);
            int nl = (l + 1 < L) ? l + 1 : -1;
            mlp_mfma_kernel<<<1024, 256, 0, stream>>>(hacc, W1, b1, W2, b2,
                                                      eps, nl, other, xbf, l, N);
            if (nl >= 0) { float* t = hacc; hacc = other; other = t; }
        }
        poolhead_kernel<<<512, 256, 0, stream>>>(hacc, starts, t_cond, hW1, hb1, hW2, hb2, out, G);
    } else {
        const float* cur = x_in;
        float* work = bufB;   // eids aliases bufA; avoid bufA as first target
        for (int l = 0; l < L; ++l) {
            float* tgt = (l == 0) ? bufB : work;
            layer_kernel<<<1024, 256, 0, stream>>>(cur, tgt, rowptr, eids, edge_index,
                                                   edge_attr, lin_e, W1, b1, W2, b2, eps, l, N, E);
            cur = tgt;
            work = (tgt == bufA) ? bufB : bufA;
        }
        poolhead_kernel<<<512, 256, 0, stream>>>(cur, starts, t_cond, hW1, hb1, hW2, hb2, out, G);
    }
}